// Round 1
// baseline (559.901 us; speedup 1.0000x reference)
//
#include <hip/hip_runtime.h>
#include <hip/hip_bf16.h>
#include <stdint.h>

// CrossAttention: B=4 T=2048 HIN=1024 H=16 E=64
// Pipeline: Wt transpose(bf16) -> fused QKV proj GEMM (bf16 MFMA) -> flash attn (bf16 MFMA)

typedef __bf16 bf16;
typedef __attribute__((ext_vector_type(8))) __bf16 bf16x8;
typedef __attribute__((ext_vector_type(4))) __bf16 bf16x4;
typedef __attribute__((ext_vector_type(4))) float f32x4;

#define B_    4
#define T_    2048
#define HIN_  1024
#define H_    16
#define E_    64
#define NOUT_ 1024
#define LOG2E 1.4426950408889634f
#define QKSCALE 0.35355339059327373f  // 64^(-0.25)

__device__ __forceinline__ void gl_lds16(const void* g, void* l) {
  // async global->LDS, 16B/lane; LDS dest = wave-uniform base + lane*16
  __builtin_amdgcn_global_load_lds((__attribute__((address_space(1))) void*)g,
                                   (__attribute__((address_space(3))) void*)l,
                                   16, 0, 0);
}

// ---------------- W transpose + fp32->bf16 convert: Wt[z][n][k] = W_z[k][n] ----------------
__global__ __launch_bounds__(256) void wt_kernel(const float* __restrict__ Wq,
                                                 const float* __restrict__ Wk,
                                                 const float* __restrict__ Wv,
                                                 bf16* __restrict__ Wt) {
  __shared__ float s[32][33];
  const int z = blockIdx.z;
  const float* W = (z == 0) ? Wq : ((z == 1) ? Wk : Wv);
  bf16* out = Wt + (size_t)z * HIN_ * NOUT_;
  const int n0 = blockIdx.x * 32, k0 = blockIdx.y * 32;
  const int tx = threadIdx.x, ty = threadIdx.y;
#pragma unroll
  for (int i = 0; i < 4; i++)
    s[ty + i * 8][tx] = W[(size_t)(k0 + ty + i * 8) * NOUT_ + n0 + tx];
  __syncthreads();
#pragma unroll
  for (int i = 0; i < 4; i++)
    out[(size_t)(n0 + ty + i * 8) * HIN_ + k0 + tx] = (bf16)s[tx][ty + i * 8];
}

// ---------------- QKV projection GEMM: C[m][n] = A[m][:] . Wt[n][:] ----------------
// z=0: Q = (Xq@Wq)*scale  -> Qb [B][H][T][E]
// z=1: K = (Xkv@Wk)*scale -> Kb [B][H][T][E]
// z=2: V = Xkv@Wv         -> Vtb [B][H][E][T]  (transposed for PV B-fragments)
__global__ __launch_bounds__(256) void proj_kernel(const float* __restrict__ Xq,
                                                   const float* __restrict__ Xkv,
                                                   const bf16* __restrict__ Wt,
                                                   bf16* __restrict__ Qb,
                                                   bf16* __restrict__ Kb,
                                                   bf16* __restrict__ Vtb) {
  __shared__ bf16 As[128 * 32];
  __shared__ bf16 Bs[128 * 32];
  const int z = blockIdx.z;
  const float* A = (z == 0) ? Xq : Xkv;
  const bf16* Bmat = Wt + (size_t)z * HIN_ * NOUT_;
  const int tid = threadIdx.x;
  const int w = tid >> 6, lane = tid & 63, quad = lane >> 4, lo = lane & 15;
  const int m0 = blockIdx.y * 128, n0 = blockIdx.x * 128;
  const int arow = tid >> 1, acol = (tid & 1) * 16;
  const int wm = (w >> 1) * 64, wn = (w & 1) * 64;

  f32x4 acc[4][4] = {};

  for (int k0 = 0; k0 < HIN_; k0 += 32) {
    __syncthreads();
    // B tile (bf16) via async direct-to-LDS: rows n, 32 k each (64B)
#pragma unroll
    for (int i = 0; i < 2; i++) {
      const bf16* g = Bmat + (size_t)(n0 + i * 64 + w * 16 + (lane >> 2)) * HIN_ + k0 + (lane & 3) * 8;
      gl_lds16(g, Bs + (i * 64 + w * 16) * 32);
    }
    // A tile: fp32 global -> cvt bf16 -> LDS (16 floats/thread = half row)
    const float* ag = A + (size_t)(m0 + arow) * HIN_ + k0 + acol;
    float4 f0 = ((const float4*)ag)[0];
    float4 f1 = ((const float4*)ag)[1];
    float4 f2 = ((const float4*)ag)[2];
    float4 f3 = ((const float4*)ag)[3];
    bf16* aw = As + arow * 32 + acol;
    bf16x4 t0 = {(bf16)f0.x, (bf16)f0.y, (bf16)f0.z, (bf16)f0.w};
    bf16x4 t1 = {(bf16)f1.x, (bf16)f1.y, (bf16)f1.z, (bf16)f1.w};
    bf16x4 t2 = {(bf16)f2.x, (bf16)f2.y, (bf16)f2.z, (bf16)f2.w};
    bf16x4 t3 = {(bf16)f3.x, (bf16)f3.y, (bf16)f3.z, (bf16)f3.w};
    ((bf16x4*)aw)[0] = t0;
    ((bf16x4*)aw)[1] = t1;
    ((bf16x4*)aw)[2] = t2;
    ((bf16x4*)aw)[3] = t3;
    __syncthreads();

    bf16x8 bfrag[4];
#pragma unroll
    for (int j = 0; j < 4; j++)
      bfrag[j] = *(const bf16x8*)(Bs + (wn + j * 16 + lo) * 32 + quad * 8);
#pragma unroll
    for (int i = 0; i < 4; i++) {
      bf16x8 afrag = *(const bf16x8*)(As + (wm + i * 16 + lo) * 32 + quad * 8);
#pragma unroll
      for (int j = 0; j < 4; j++)
        acc[i][j] = __builtin_amdgcn_mfma_f32_16x16x32_bf16(afrag, bfrag[j], acc[i][j], 0, 0, 0);
    }
  }

  // epilogue: C/D layout col=lane&15, row=quad*4+reg
#pragma unroll
  for (int i = 0; i < 4; i++)
#pragma unroll
    for (int j = 0; j < 4; j++)
#pragma unroll
      for (int r = 0; r < 4; r++) {
        int m = m0 + wm + i * 16 + quad * 4 + r;
        int n = n0 + wn + j * 16 + lo;
        int b = m >> 11, t = m & 2047, h = n >> 6, e = n & 63;
        float v = acc[i][j][r];
        if (z == 0)
          Qb[(((size_t)b * H_ + h) * T_ + t) * E_ + e] = (bf16)(v * QKSCALE);
        else if (z == 1)
          Kb[(((size_t)b * H_ + h) * T_ + t) * E_ + e] = (bf16)(v * QKSCALE);
        else
          Vtb[(((size_t)b * H_ + h) * E_ + e) * T_ + t] = (bf16)v;
      }
}

// ---------------- Flash attention: per (b,h), 128 q-rows per block, 64-key tiles ----------------
__global__ __launch_bounds__(256) void attn_kernel(const bf16* __restrict__ Qb,
                                                   const bf16* __restrict__ Kb,
                                                   const bf16* __restrict__ Vtb,
                                                   float* __restrict__ out) {
  __shared__ bf16 Qs[128 * 64];
  __shared__ bf16 Ks[64 * 64];
  __shared__ bf16 Vts[64 * 64];
  __shared__ bf16 Ps[128 * 64];
  const int tid = threadIdx.x;
  const int w = tid >> 6, lane = tid & 63, quad = lane >> 4, lo = lane & 15;
  const int bh = blockIdx.y;
  const int q0 = blockIdx.x * 128;
  const bf16* Qg = Qb + ((size_t)bh * T_ + q0) * E_;
  const bf16* Kg = Kb + (size_t)bh * T_ * E_;
  const bf16* Vg = Vtb + (size_t)bh * E_ * T_;

  // stage Q once (async; drained by first in-loop barrier)
#pragma unroll
  for (int i = 0; i < 4; i++) {
    const bf16* g = Qg + (size_t)(i * 32 + w * 8 + (lane >> 3)) * E_ + (lane & 7) * 8;
    gl_lds16(g, Qs + (i * 32 + w * 8) * E_);
  }

  f32x4 acc_o[2][4] = {};
  float m_run[2][4], l_run[2][4];
#pragma unroll
  for (int mi = 0; mi < 2; mi++)
#pragma unroll
    for (int r = 0; r < 4; r++) { m_run[mi][r] = -1e30f; l_run[mi][r] = 0.f; }

  for (int kt = 0; kt < T_ / 64; kt++) {
    __syncthreads();  // prev iter done with Ks/Vts
#pragma unroll
    for (int i = 0; i < 2; i++) {  // K tile rows t (64 x 64e)
      const bf16* g = Kg + (size_t)(kt * 64 + i * 32 + w * 8 + (lane >> 3)) * E_ + (lane & 7) * 8;
      gl_lds16(g, Ks + (i * 32 + w * 8) * 64);
    }
#pragma unroll
    for (int i = 0; i < 2; i++) {  // Vt tile rows e (64 x 64t)
      const bf16* g = Vg + (size_t)(i * 32 + w * 8 + (lane >> 3)) * T_ + kt * 64 + (lane & 7) * 8;
      gl_lds16(g, Vts + (i * 32 + w * 8) * 64);
    }
    __syncthreads();

    // S = Q @ K^T   (wave owns rows 32w..32w+31)
    bf16x8 kfrag[4][2];
#pragma unroll
    for (int nj = 0; nj < 4; nj++)
#pragma unroll
      for (int ks = 0; ks < 2; ks++)
        kfrag[nj][ks] = *(const bf16x8*)(Ks + (nj * 16 + lo) * 64 + ks * 32 + quad * 8);
    f32x4 s[2][4] = {};
#pragma unroll
    for (int mi = 0; mi < 2; mi++)
#pragma unroll
      for (int ks = 0; ks < 2; ks++) {
        bf16x8 qf = *(const bf16x8*)(Qs + (w * 32 + mi * 16 + lo) * 64 + ks * 32 + quad * 8);
#pragma unroll
        for (int nj = 0; nj < 4; nj++)
          s[mi][nj] = __builtin_amdgcn_mfma_f32_16x16x32_bf16(qf, kfrag[nj][ks], s[mi][nj], 0, 0, 0);
      }

    // online softmax (rows owned by quad group; reduce across lanes 0..15 via xor shuffles)
#pragma unroll
    for (int mi = 0; mi < 2; mi++)
#pragma unroll
      for (int r = 0; r < 4; r++) {
        float rmax = fmaxf(fmaxf(s[mi][0][r], s[mi][1][r]), fmaxf(s[mi][2][r], s[mi][3][r]));
#pragma unroll
        for (int d = 1; d < 16; d <<= 1) rmax = fmaxf(rmax, __shfl_xor(rmax, d));
        float mn = fmaxf(m_run[mi][r], rmax);
        float al = exp2f((m_run[mi][r] - mn) * LOG2E);
        float rs = 0.f;
#pragma unroll
        for (int nj = 0; nj < 4; nj++) {
          float p = exp2f((s[mi][nj][r] - mn) * LOG2E);
          s[mi][nj][r] = p;
          rs += p;
        }
#pragma unroll
        for (int d = 1; d < 16; d <<= 1) rs += __shfl_xor(rs, d);
        l_run[mi][r] = l_run[mi][r] * al + rs;
        m_run[mi][r] = mn;
#pragma unroll
        for (int ej = 0; ej < 4; ej++) acc_o[mi][ej][r] *= al;
      }

    // P (C-layout regs) -> LDS -> A-layout fragments; rows are wave-private, no barrier needed
#pragma unroll
    for (int mi = 0; mi < 2; mi++)
#pragma unroll
      for (int nj = 0; nj < 4; nj++)
#pragma unroll
        for (int r = 0; r < 4; r++)
          Ps[(w * 32 + mi * 16 + quad * 4 + r) * 64 + nj * 16 + lo] = (bf16)s[mi][nj][r];

    // O += P @ V
    bf16x8 vfrag[4][2];
#pragma unroll
    for (int ej = 0; ej < 4; ej++)
#pragma unroll
      for (int ks = 0; ks < 2; ks++)
        vfrag[ej][ks] = *(const bf16x8*)(Vts + (ej * 16 + lo) * 64 + ks * 32 + quad * 8);
#pragma unroll
    for (int mi = 0; mi < 2; mi++)
#pragma unroll
      for (int ks = 0; ks < 2; ks++) {
        bf16x8 pf = *(const bf16x8*)(Ps + (w * 32 + mi * 16 + lo) * 64 + ks * 32 + quad * 8);
#pragma unroll
        for (int ej = 0; ej < 4; ej++)
          acc_o[mi][ej] = __builtin_amdgcn_mfma_f32_16x16x32_bf16(pf, vfrag[ej][ks], acc_o[mi][ej], 0, 0, 0);
      }
  }

  const int b = bh >> 4, h = bh & 15;
#pragma unroll
  for (int mi = 0; mi < 2; mi++)
#pragma unroll
    for (int r = 0; r < 4; r++) {
      float inv = 1.f / l_run[mi][r];
      int t = q0 + w * 32 + mi * 16 + quad * 4 + r;
#pragma unroll
      for (int ej = 0; ej < 4; ej++)
        out[(size_t)(b * T_ + t) * NOUT_ + h * E_ + ej * 16 + lo] = acc_o[mi][ej][r] * inv;
    }
}

extern "C" void kernel_launch(void* const* d_in, const int* in_sizes, int n_in,
                              void* d_out, int out_size, void* d_ws, size_t ws_size,
                              hipStream_t stream) {
  const float* Xq  = (const float*)d_in[0];
  const float* Xkv = (const float*)d_in[1];
  const float* Wq  = (const float*)d_in[2];
  const float* Wk  = (const float*)d_in[3];
  const float* Wv  = (const float*)d_in[4];
  float* out = (float*)d_out;

  char* ws = (char*)d_ws;
  bf16* Qb  = (bf16*)(ws);                        // 16 MB  [B][H][T][E]
  bf16* Kb  = (bf16*)(ws + ((size_t)16 << 20));   // 16 MB  [B][H][T][E]
  bf16* Vtb = (bf16*)(ws + ((size_t)32 << 20));   // 16 MB  [B][H][E][T]
  bf16* Wt  = (bf16*)(ws + ((size_t)48 << 20));   // 6 MB   3 x [N][K]

  hipLaunchKernelGGL(wt_kernel, dim3(32, 32, 3), dim3(32, 8), 0, stream, Wq, Wk, Wv, Wt);
  hipLaunchKernelGGL(proj_kernel, dim3(8, 64, 3), dim3(256), 0, stream, Xq, Xkv, Wt, Qb, Kb, Vtb);
  hipLaunchKernelGGL(attn_kernel, dim3(16, 64), dim3(256), 0, stream, Qb, Kb, Vtb, out);
}

// Round 2
// 416.142 us; speedup vs baseline: 1.3455x; 1.3455x over previous
//
#include <hip/hip_runtime.h>
#include <hip/hip_bf16.h>
#include <stdint.h>

// CrossAttention: B=4 T=2048 HIN=1024 H=16 E=64
// Wt transpose+swizzle -> fused QKV proj GEMM (bf16 MFMA, BK=64) -> flash attn (no-max softmax)
// LDS conflict strategy: 16B-chunk XOR swizzles; K/V swizzled in GLOBAL by proj so
// global_load_lds staging (contiguous lane order) stays legal.

typedef __bf16 bf16;
typedef __attribute__((ext_vector_type(8))) __bf16 bf16x8;
typedef __attribute__((ext_vector_type(4))) __bf16 bf16x4;
typedef __attribute__((ext_vector_type(4))) float f32x4;

#define B_    4
#define T_    2048
#define HIN_  1024
#define H_    16
#define E_    64
#define NOUT_ 1024
#define LOG2E 1.4426950408889634f
#define QKSCALE 0.35355339059327373f  // 64^(-0.25)

__device__ __forceinline__ void gl_lds16(const void* g, void* l) {
  __builtin_amdgcn_global_load_lds((__attribute__((address_space(1))) void*)g,
                                   (__attribute__((address_space(3))) void*)l,
                                   16, 0, 0);
}

// ---- W transpose + fp32->bf16 + chunk swizzle: Wt[z][n][ksw], ksw chunk ^= n&7 in 64-k window ----
__global__ __launch_bounds__(256) void wt_kernel(const float* __restrict__ Wq,
                                                 const float* __restrict__ Wk,
                                                 const float* __restrict__ Wv,
                                                 bf16* __restrict__ Wt) {
  __shared__ float s[32][33];
  const int z = blockIdx.z;
  const float* W = (z == 0) ? Wq : ((z == 1) ? Wk : Wv);
  bf16* out = Wt + (size_t)z * HIN_ * NOUT_;
  const int n0 = blockIdx.x * 32, k0 = blockIdx.y * 32;
  const int tx = threadIdx.x, ty = threadIdx.y;
#pragma unroll
  for (int i = 0; i < 4; i++)
    s[ty + i * 8][tx] = W[(size_t)(k0 + ty + i * 8) * NOUT_ + n0 + tx];
  __syncthreads();
#pragma unroll
  for (int i = 0; i < 4; i++) {
    int n = n0 + ty + i * 8;
    int k = k0 + tx;
    int ksw = (k & ~63) | ((((k >> 3) & 7) ^ (n & 7)) << 3) | (k & 7);
    out[(size_t)n * HIN_ + ksw] = (bf16)s[tx][ty + i * 8];
  }
}

// ---- QKV projection GEMM, 128x128 tile, BK=64 ----
// z=0: Q*scale -> Qb [B][H][T][E] linear
// z=1: K*scale -> Kb [B][H][T][Esw]  (e-chunk ^= t&7)
// z=2: V       -> Vtb [B][H][E][Tsw] (t-chunk within 64-window ^= e&7)
__global__ __launch_bounds__(256) void proj_kernel(const float* __restrict__ Xq,
                                                   const float* __restrict__ Xkv,
                                                   const bf16* __restrict__ Wt,
                                                   bf16* __restrict__ Qb,
                                                   bf16* __restrict__ Kb,
                                                   bf16* __restrict__ Vtb) {
  __shared__ bf16 As[128 * 72];  // padded: stride 72 elem = 144 B -> conflict-free b128 reads
  __shared__ bf16 Bs[128 * 64];  // global-load-lds staged; Wt pre-swizzled for free reads
  const int z = blockIdx.z;
  const float* A = (z == 0) ? Xq : Xkv;
  const bf16* Bmat = Wt + (size_t)z * HIN_ * NOUT_;
  const int tid = threadIdx.x;
  const int w = tid >> 6, lane = tid & 63, quad = lane >> 4, lo = lane & 15;
  const int m0 = blockIdx.y * 128, n0 = blockIdx.x * 128;
  const int arow = tid >> 1, acol = (tid & 1) * 32;
  const int wm = (w >> 1) * 64, wn = (w & 1) * 64;

  f32x4 acc[4][4] = {};

  for (int k0 = 0; k0 < HIN_; k0 += 64) {
    __syncthreads();
#pragma unroll
    for (int j = 0; j < 4; j++) {
      const bf16* g = Bmat + (size_t)(n0 + j * 32 + w * 8 + (lane >> 3)) * HIN_ + k0 + (lane & 7) * 8;
      gl_lds16(g, Bs + (j * 32 + w * 8) * 64);
    }
    const float* ag = A + (size_t)(m0 + arow) * HIN_ + k0 + acol;
    bf16* aw = As + arow * 72 + acol;
#pragma unroll
    for (int i = 0; i < 4; i++) {
      float4 f0 = ((const float4*)ag)[2 * i];
      float4 f1 = ((const float4*)ag)[2 * i + 1];
      bf16x8 t = {(bf16)f0.x, (bf16)f0.y, (bf16)f0.z, (bf16)f0.w,
                  (bf16)f1.x, (bf16)f1.y, (bf16)f1.z, (bf16)f1.w};
      ((bf16x8*)aw)[i] = t;
    }
    __syncthreads();

#pragma unroll
    for (int kk = 0; kk < 2; kk++) {
      bf16x8 bfrag[4];
#pragma unroll
      for (int j = 0; j < 4; j++)
        bfrag[j] = *(const bf16x8*)(Bs + (wn + j * 16 + lo) * 64 + ((((kk << 2) + quad) ^ (lo & 7)) << 3));
#pragma unroll
      for (int i = 0; i < 4; i++) {
        bf16x8 afrag = *(const bf16x8*)(As + (wm + i * 16 + lo) * 72 + kk * 32 + quad * 8);
#pragma unroll
        for (int j = 0; j < 4; j++)
          acc[i][j] = __builtin_amdgcn_mfma_f32_16x16x32_bf16(afrag, bfrag[j], acc[i][j], 0, 0, 0);
      }
    }
  }

  // epilogue: C/D layout col=lane&15, row=quad*4+reg
#pragma unroll
  for (int i = 0; i < 4; i++)
#pragma unroll
    for (int j = 0; j < 4; j++)
#pragma unroll
      for (int r = 0; r < 4; r++) {
        int m = m0 + wm + i * 16 + quad * 4 + r;
        int n = n0 + wn + j * 16 + lo;
        int b = m >> 11, t = m & 2047, h = n >> 6, e = n & 63;
        float v = acc[i][j][r];
        if (z == 0) {
          Qb[(((size_t)b * H_ + h) * T_ + t) * E_ + e] = (bf16)(v * QKSCALE);
        } else if (z == 1) {
          int esw = ((((e >> 3) ^ (t & 7)) << 3) | (e & 7));
          Kb[(((size_t)b * H_ + h) * T_ + t) * E_ + esw] = (bf16)(v * QKSCALE);
        } else {
          int tsw = (t & ~63) | (((((t >> 3) & 7) ^ (e & 7)) << 3) | (t & 7));
          Vtb[(((size_t)b * H_ + h) * E_ + e) * T_ + tsw] = (bf16)v;
        }
      }
}

// ---- Flash attention: per (b,h), 128 q-rows/block, 64-key tiles, no-max softmax ----
__global__ __launch_bounds__(256) void attn_kernel(const bf16* __restrict__ Qb,
                                                   const bf16* __restrict__ Kb,
                                                   const bf16* __restrict__ Vtb,
                                                   float* __restrict__ out) {
  __shared__ bf16 Ks[64 * 64];
  __shared__ bf16 Vts[64 * 64];
  __shared__ bf16 Ps[128 * 64];  // chunk ^= (row>>1)&7 : conflict-free writes AND reads
  const int tid = threadIdx.x;
  const int w = tid >> 6, lane = tid & 63, quad = lane >> 4, lo = lane & 15;
  const int bh = blockIdx.y, q0 = blockIdx.x * 128;
  const bf16* Qg = Qb + ((size_t)bh * T_ + q0) * E_;
  const bf16* Kg = Kb + (size_t)bh * T_ * E_;
  const bf16* Vg = Vtb + (size_t)bh * E_ * T_;

  // Q fragments: registers for the whole loop (Q is linear in global)
  bf16x8 qf[2][2];
#pragma unroll
  for (int mi = 0; mi < 2; mi++)
#pragma unroll
    for (int ks = 0; ks < 2; ks++)
      qf[mi][ks] = *(const bf16x8*)(Qg + (size_t)(w * 32 + mi * 16 + lo) * E_ + ks * 32 + quad * 8);

  f32x4 acc_o[2][4] = {};
  float lsum[2][4] = {{0.f, 0.f, 0.f, 0.f}, {0.f, 0.f, 0.f, 0.f}};
  const int sw = lo & 7;           // K/V read swizzle (t&7 / e&7 of the lane's row)
  const int psw = (lo >> 1) & 7;   // Ps read swizzle ((row>>1)&7)

  for (int kt = 0; kt < T_ / 64; kt++) {
    __syncthreads();
#pragma unroll
    for (int i = 0; i < 2; i++) {
      const bf16* g = Kg + (size_t)(kt * 64 + i * 32 + w * 8 + (lane >> 3)) * E_ + (lane & 7) * 8;
      gl_lds16(g, Ks + (i * 32 + w * 8) * 64);
    }
#pragma unroll
    for (int i = 0; i < 2; i++) {
      const bf16* g = Vg + (size_t)(i * 32 + w * 8 + (lane >> 3)) * T_ + kt * 64 + (lane & 7) * 8;
      gl_lds16(g, Vts + (i * 32 + w * 8) * 64);
    }
    __syncthreads();

    // S = Q @ K^T
    bf16x8 kfrag[4][2];
#pragma unroll
    for (int nj = 0; nj < 4; nj++)
#pragma unroll
      for (int ks = 0; ks < 2; ks++)
        kfrag[nj][ks] = *(const bf16x8*)(Ks + (nj * 16 + lo) * 64 + ((((ks << 2) + quad) ^ sw) << 3));
    f32x4 s[2][4] = {};
#pragma unroll
    for (int mi = 0; mi < 2; mi++)
#pragma unroll
      for (int ks = 0; ks < 2; ks++)
#pragma unroll
        for (int nj = 0; nj < 4; nj++)
          s[mi][nj] = __builtin_amdgcn_mfma_f32_16x16x32_bf16(qf[mi][ks], kfrag[nj][ks], s[mi][nj], 0, 0, 0);

    // no-max softmax: p = exp(s); per-lane partial row sums (reduced once at the end)
#pragma unroll
    for (int mi = 0; mi < 2; mi++)
#pragma unroll
      for (int nj = 0; nj < 4; nj++) {
        const int ch = (nj * 16 + lo) >> 3;
#pragma unroll
        for (int r = 0; r < 4; r++) {
          float p = exp2f(s[mi][nj][r] * LOG2E);
          lsum[mi][r] += p;
          int row = w * 32 + mi * 16 + quad * 4 + r;
          Ps[row * 64 + ((ch ^ ((row >> 1) & 7)) << 3) + (lo & 7)] = (bf16)p;
        }
      }

    // O += P @ V
    bf16x8 vfrag[4][2];
#pragma unroll
    for (int ej = 0; ej < 4; ej++)
#pragma unroll
      for (int ks = 0; ks < 2; ks++)
        vfrag[ej][ks] = *(const bf16x8*)(Vts + (ej * 16 + lo) * 64 + ((((ks << 2) + quad) ^ sw) << 3));
#pragma unroll
    for (int mi = 0; mi < 2; mi++) {
      const int prow = w * 32 + mi * 16 + lo;
#pragma unroll
      for (int ks = 0; ks < 2; ks++) {
        bf16x8 pf = *(const bf16x8*)(Ps + prow * 64 + ((((ks << 2) + quad) ^ psw) << 3));
#pragma unroll
        for (int ej = 0; ej < 4; ej++)
          acc_o[mi][ej] = __builtin_amdgcn_mfma_f32_16x16x32_bf16(pf, vfrag[ej][ks], acc_o[mi][ej], 0, 0, 0);
      }
    }
  }

  const int b = bh >> 4, h = bh & 15;
#pragma unroll
  for (int mi = 0; mi < 2; mi++)
#pragma unroll
    for (int r = 0; r < 4; r++) {
      float l = lsum[mi][r];
#pragma unroll
      for (int d = 1; d < 16; d <<= 1) l += __shfl_xor(l, d);
      float inv = 1.f / l;
      int t = q0 + w * 32 + mi * 16 + quad * 4 + r;
#pragma unroll
      for (int ej = 0; ej < 4; ej++)
        out[(size_t)(b * T_ + t) * NOUT_ + h * E_ + ej * 16 + lo] = acc_o[mi][ej][r] * inv;
    }
}

extern "C" void kernel_launch(void* const* d_in, const int* in_sizes, int n_in,
                              void* d_out, int out_size, void* d_ws, size_t ws_size,
                              hipStream_t stream) {
  const float* Xq  = (const float*)d_in[0];
  const float* Xkv = (const float*)d_in[1];
  const float* Wq  = (const float*)d_in[2];
  const float* Wk  = (const float*)d_in[3];
  const float* Wv  = (const float*)d_in[4];
  float* out = (float*)d_out;

  char* ws = (char*)d_ws;
  bf16* Qb  = (bf16*)(ws);                        // 16 MB [B][H][T][E] linear
  bf16* Kb  = (bf16*)(ws + ((size_t)16 << 20));   // 16 MB [B][H][T][E] swizzled
  bf16* Vtb = (bf16*)(ws + ((size_t)32 << 20));   // 16 MB [B][H][E][T] swizzled
  bf16* Wt  = (bf16*)(ws + ((size_t)48 << 20));   // 6 MB  3 x [N][K] swizzled

  hipLaunchKernelGGL(wt_kernel, dim3(32, 32, 3), dim3(32, 8), 0, stream, Wq, Wk, Wv, Wt);
  hipLaunchKernelGGL(proj_kernel, dim3(8, 64, 3), dim3(256), 0, stream, Xq, Xkv, Wt, Qb, Kb, Vtb);
  hipLaunchKernelGGL(attn_kernel, dim3(16, 64), dim3(256), 0, stream, Qb, Kb, Vtb, out);
}

// Round 3
// 302.849 us; speedup vs baseline: 1.8488x; 1.3741x over previous
//
#include <hip/hip_runtime.h>
#include <hip/hip_bf16.h>
#include <stdint.h>

// CrossAttention: B=4 T=2048 HIN=1024 H=16 E=64
// cvt(X->bf16, scratch=d_out) + Wt transpose -> all-bf16 proj GEMM (async LDS both operands)
// -> flash attn computing S^T=K*Q^T so P lands in 16x16x16 A-fragment layout (no P LDS trip).
// Bank-conflict strategy: XOR of 16B chunk index applied to the *global source address* at
// global_load_lds staging time (per-lane global addr is legal; LDS dest stays linear).

typedef __bf16 bf16;
typedef __attribute__((ext_vector_type(8))) __bf16 bf16x8;
typedef __attribute__((ext_vector_type(4))) __bf16 bf16x4;
typedef __attribute__((ext_vector_type(4))) float f32x4;
typedef __attribute__((ext_vector_type(4))) short s16x4;

#define B_    4
#define T_    2048
#define HIN_  1024
#define H_    16
#define E_    64
#define NOUT_ 1024
#define LOG2E 1.4426950408889634f
#define QKSCALE 0.35355339059327373f  // 64^(-0.25)

__device__ __forceinline__ void gl_lds16(const void* g, void* l) {
  __builtin_amdgcn_global_load_lds((__attribute__((address_space(1))) void*)g,
                                   (__attribute__((address_space(3))) void*)l,
                                   16, 0, 0);
}

// ---- X fp32 -> bf16 ----
__global__ __launch_bounds__(256) void cvt_kernel(const float* __restrict__ Xq,
                                                  const float* __restrict__ Xkv,
                                                  bf16* __restrict__ Xb) {
  const float* src = blockIdx.y ? Xkv : Xq;
  bf16* dst = Xb + (size_t)blockIdx.y * (8192 * 1024);
  size_t i = ((size_t)blockIdx.x * 256 + threadIdx.x) * 8;
  float4 f0 = ((const float4*)(src + i))[0];
  float4 f1 = ((const float4*)(src + i))[1];
  bf16x8 t = {(bf16)f0.x, (bf16)f0.y, (bf16)f0.z, (bf16)f0.w,
              (bf16)f1.x, (bf16)f1.y, (bf16)f1.z, (bf16)f1.w};
  *(bf16x8*)(dst + i) = t;
}

// ---- W transpose + fp32->bf16: Wt[z][n][k] = W_z[k][n] (linear) ----
__global__ __launch_bounds__(256) void wt_kernel(const float* __restrict__ Wq,
                                                 const float* __restrict__ Wk,
                                                 const float* __restrict__ Wv,
                                                 bf16* __restrict__ Wt) {
  __shared__ float s[32][33];
  const int z = blockIdx.z;
  const float* W = (z == 0) ? Wq : ((z == 1) ? Wk : Wv);
  bf16* out = Wt + (size_t)z * HIN_ * NOUT_;
  const int n0 = blockIdx.x * 32, k0 = blockIdx.y * 32;
  const int tx = threadIdx.x, ty = threadIdx.y;
#pragma unroll
  for (int i = 0; i < 4; i++)
    s[ty + i * 8][tx] = W[(size_t)(k0 + ty + i * 8) * NOUT_ + n0 + tx];
  __syncthreads();
#pragma unroll
  for (int i = 0; i < 4; i++)
    out[(size_t)(n0 + ty + i * 8) * HIN_ + k0 + tx] = (bf16)s[tx][ty + i * 8];
}

// ---- QKV projection, all-bf16, 128x128 tile, BK=64, both operands async-staged ----
// z=0: C[t][n]=Xq.Wq*s -> Qb [B][H][T][E];  z=1: same with Wk -> Kb
// z=2: C[oc][t]=Wv^T.Xkv -> Vtb [B][H][E][T] (coalesced epilogue)
__global__ __launch_bounds__(256, 2) void proj_kernel(const bf16* __restrict__ Xb,
                                                      const bf16* __restrict__ Wt,
                                                      bf16* __restrict__ Qb,
                                                      bf16* __restrict__ Kb,
                                                      bf16* __restrict__ Vtb) {
  __shared__ bf16 As[128 * 64];
  __shared__ bf16 Bs[128 * 64];
  const int z = blockIdx.z;
  const bf16* Abase = (z == 0) ? Xb : ((z == 1) ? Xb + (size_t)8192 * 1024 : Wt + (size_t)2 * HIN_ * NOUT_);
  const bf16* Bbase = (z == 0) ? Wt : ((z == 1) ? Wt + (size_t)HIN_ * NOUT_ : Xb + (size_t)8192 * 1024);
  const int mt = (z == 2) ? blockIdx.x : blockIdx.y;
  const int nt = (z == 2) ? blockIdx.y : blockIdx.x;
  const int m0 = mt * 128, n0 = nt * 128;
  const int tid = threadIdx.x;
  const int w = tid >> 6, lane = tid & 63, quad = lane >> 4, lo = lane & 15;
  const int wm = (w >> 1) * 64, wn = (w & 1) * 64;
  const int srow = w * 8 + (lane >> 3);          // staging row within 32-row group
  const int schunk = (lane & 7) ^ (srow & 7);    // XOR'd source chunk

  f32x4 acc[4][4] = {};

  for (int k0 = 0; k0 < HIN_; k0 += 64) {
    __syncthreads();
#pragma unroll
    for (int j = 0; j < 4; j++) {
      int row = j * 32 + srow;
      gl_lds16(Abase + (size_t)(m0 + row) * HIN_ + k0 + schunk * 8, As + (j * 32 + w * 8) * 64);
      gl_lds16(Bbase + (size_t)(n0 + row) * HIN_ + k0 + schunk * 8, Bs + (j * 32 + w * 8) * 64);
    }
    __syncthreads();
#pragma unroll
    for (int kk = 0; kk < 2; kk++) {
      bf16x8 bfrag[4], afrag[4];
#pragma unroll
      for (int j = 0; j < 4; j++) {
        int off = ((((kk << 2) + quad) ^ (lo & 7)) << 3);
        bfrag[j] = *(const bf16x8*)(Bs + (wn + j * 16 + lo) * 64 + off);
        afrag[j] = *(const bf16x8*)(As + (wm + j * 16 + lo) * 64 + off);
      }
#pragma unroll
      for (int i = 0; i < 4; i++)
#pragma unroll
        for (int j = 0; j < 4; j++)
          acc[i][j] = __builtin_amdgcn_mfma_f32_16x16x32_bf16(afrag[i], bfrag[j], acc[i][j], 0, 0, 0);
    }
  }

  // epilogue: C/D layout col=lane&15, row=quad*4+reg
#pragma unroll
  for (int i = 0; i < 4; i++)
#pragma unroll
    for (int j = 0; j < 4; j++)
#pragma unroll
      for (int r = 0; r < 4; r++) {
        int m = m0 + wm + i * 16 + quad * 4 + r;
        int n = n0 + wn + j * 16 + lo;
        float v = acc[i][j][r];
        if (z == 2) {
          int h = m >> 6, e = m & 63, b = n >> 11, t = n & 2047;
          Vtb[(((size_t)b * H_ + h) * E_ + e) * T_ + t] = (bf16)v;
        } else {
          int b = m >> 11, t = m & 2047, h = n >> 6, e = n & 63;
          bf16* dst = (z == 0) ? Qb : Kb;
          dst[(((size_t)b * H_ + h) * T_ + t) * E_ + e] = (bf16)(v * QKSCALE);
        }
      }
}

// ---- Flash attention: S^T = K*Q^T so P is already in 16x16x16 A-fragment layout ----
// block = 256 q-rows (64/wave), k-tiles of 64; grid (bh, qchunk) for XCD L2 locality.
__global__ __launch_bounds__(256, 2) void attn_kernel(const bf16* __restrict__ Qb,
                                                      const bf16* __restrict__ Kb,
                                                      const bf16* __restrict__ Vtb,
                                                      float* __restrict__ out) {
  __shared__ bf16 Ks[64 * 64];
  __shared__ bf16 Vts[64 * 64];
  const int tid = threadIdx.x;
  const int w = tid >> 6, lane = tid & 63, quad = lane >> 4, lo = lane & 15;
  const int bh = blockIdx.x, q0 = blockIdx.y * 256;
  const int wq = q0 + w * 64;
  const bf16* Qg = Qb + (size_t)bh * T_ * E_;
  const bf16* Kg = Kb + (size_t)bh * T_ * E_;
  const bf16* Vg = Vtb + (size_t)bh * E_ * T_;
  const int srow = w * 8 + (lane >> 3);
  const int schunk = (lane & 7) ^ (srow & 7);

  // Q fragments in registers for the whole loop (B-operand: n=lo -> q, k=quad*8+j -> e)
  bf16x8 qf[4][2];
#pragma unroll
  for (int qi = 0; qi < 4; qi++)
#pragma unroll
    for (int ks = 0; ks < 2; ks++)
      qf[qi][ks] = *(const bf16x8*)(Qg + (size_t)(wq + qi * 16 + lo) * E_ + ks * 32 + quad * 8);

  f32x4 acc[4][4] = {};  // [qi][ej]  rows q=quad*4+r, cols e=lo
  float lsum[4] = {0.f, 0.f, 0.f, 0.f};

  for (int kt = 0; kt < T_ / 64; kt++) {
    __syncthreads();
#pragma unroll
    for (int i = 0; i < 2; i++) {
      int row = i * 32 + srow;
      gl_lds16(Kg + (size_t)(kt * 64 + row) * E_ + schunk * 8, Ks + (i * 32 + w * 8) * 64);
      gl_lds16(Vg + (size_t)row * T_ + kt * 64 + schunk * 8, Vts + (i * 32 + w * 8) * 64);
    }
    __syncthreads();

    // K fragments (A-operand: m=lo -> t, k=quad*8+j -> e)
    bf16x8 kf[4][2];
#pragma unroll
    for (int ti = 0; ti < 4; ti++)
#pragma unroll
      for (int ks = 0; ks < 2; ks++)
        kf[ti][ks] = *(const bf16x8*)(Ks + (ti * 16 + lo) * 64 + ((((ks << 2) + quad) ^ (lo & 7)) << 3));

    // S^T tiles + exp -> P fragments (A-layout for 16x16x16: k=quad*4+j == C-row quad*4+r)
    bf16x4 pf[4][4];  // [qi][ti]
#pragma unroll
    for (int qi = 0; qi < 4; qi++) {
      f32x4 st[4] = {};
#pragma unroll
      for (int ks = 0; ks < 2; ks++)
#pragma unroll
        for (int ti = 0; ti < 4; ti++)
          st[ti] = __builtin_amdgcn_mfma_f32_16x16x32_bf16(kf[ti][ks], qf[qi][ks], st[ti], 0, 0, 0);
      float ls = 0.f;
#pragma unroll
      for (int ti = 0; ti < 4; ti++) {
        bf16x4 p4;
#pragma unroll
        for (int r = 0; r < 4; r++) {
          float p = exp2f(st[ti][r] * LOG2E);
          ls += p;
          p4[r] = (bf16)p;
        }
        pf[qi][ti] = p4;
      }
      lsum[qi] += ls;
    }

    // O += P @ V  via 16x16x16 (B-operand: n=lo -> e, k=quad*4+j -> t)
#pragma unroll
    for (int tc = 0; tc < 4; tc++)
#pragma unroll
      for (int ej = 0; ej < 4; ej++) {
        bf16x4 vf = *(const bf16x4*)(Vts + (ej * 16 + lo) * 64 +
                                     (((tc * 2 + (quad >> 1)) ^ (lo & 7)) << 3) + (quad & 1) * 4);
#pragma unroll
        for (int qi = 0; qi < 4; qi++)
          acc[qi][ej] = __builtin_amdgcn_mfma_f32_16x16x16bf16_1k(
              __builtin_bit_cast(s16x4, pf[qi][tc]), __builtin_bit_cast(s16x4, vf),
              acc[qi][ej], 0, 0, 0);
      }
  }

  const int b = bh >> 4, h = bh & 15;
#pragma unroll
  for (int qi = 0; qi < 4; qi++) {
    float l = lsum[qi];
    l += __shfl_xor(l, 16);
    l += __shfl_xor(l, 32);  // all quads now hold full sum for q = qi*16+lo
#pragma unroll
    for (int r = 0; r < 4; r++) {
      float linv = 1.f / __shfl(l, quad * 4 + r);
      size_t t = q0 + w * 64 + qi * 16 + quad * 4 + r;
#pragma unroll
      for (int ej = 0; ej < 4; ej++)
        out[((size_t)b * T_ + t) * NOUT_ + h * E_ + ej * 16 + lo] = acc[qi][ej][r] * linv;
    }
  }
}

extern "C" void kernel_launch(void* const* d_in, const int* in_sizes, int n_in,
                              void* d_out, int out_size, void* d_ws, size_t ws_size,
                              hipStream_t stream) {
  const float* Xq  = (const float*)d_in[0];
  const float* Xkv = (const float*)d_in[1];
  const float* Wq  = (const float*)d_in[2];
  const float* Wk  = (const float*)d_in[3];
  const float* Wv  = (const float*)d_in[4];
  float* out = (float*)d_out;

  char* ws = (char*)d_ws;
  bf16* Qb  = (bf16*)(ws);                        // 16 MB [B][H][T][E]
  bf16* Kb  = (bf16*)(ws + ((size_t)16 << 20));   // 16 MB [B][H][T][E]
  bf16* Vtb = (bf16*)(ws + ((size_t)32 << 20));   // 16 MB [B][H][E][T]
  bf16* Wt  = (bf16*)(ws + ((size_t)48 << 20));   // 6 MB  3 x [N][K]
  bf16* Xb  = (bf16*)d_out;                       // 32 MB scratch: d_out unread until attn overwrites it

  hipLaunchKernelGGL(cvt_kernel, dim3(4096, 2), dim3(256), 0, stream, Xq, Xkv, Xb);
  hipLaunchKernelGGL(wt_kernel, dim3(32, 32, 3), dim3(32, 8), 0, stream, Wq, Wk, Wv, Wt);
  hipLaunchKernelGGL(proj_kernel, dim3(8, 64, 3), dim3(256), 0, stream, Xb, Wt, Qb, Kb, Vtb);
  hipLaunchKernelGGL(attn_kernel, dim3(64, 8), dim3(256), 0, stream, Qb, Kb, Vtb, out);
}

// Round 4
// 260.674 us; speedup vs baseline: 2.1479x; 1.1618x over previous
//
#include <hip/hip_runtime.h>
#include <hip/hip_bf16.h>
#include <stdint.h>

// CrossAttention: B=4 T=2048 HIN=1024 H=16 E=64
// cvt(X->bf16, scratch=d_out) + Wt transpose -> all-bf16 proj GEMM (async LDS both operands,
// XCD-aware grid) -> flash attn (S^T=K*Q^T so P is A-fragment-native; raw v_exp_f32;
// LOG2E folded into Q's stored scale; 2-wave blocks for 4 blocks/CU).

typedef __bf16 bf16;
typedef __attribute__((ext_vector_type(8))) __bf16 bf16x8;
typedef __attribute__((ext_vector_type(4))) __bf16 bf16x4;
typedef __attribute__((ext_vector_type(4))) float f32x4;
typedef __attribute__((ext_vector_type(4))) short s16x4;

#define B_    4
#define T_    2048
#define HIN_  1024
#define H_    16
#define E_    64
#define NOUT_ 1024
#define LOG2E 1.4426950408889634f
#define QKSCALE 0.35355339059327373f   // 64^(-0.25)
#define QSCALE  (QKSCALE * LOG2E)      // fold log2(e) into Q so p = exp2(S) directly

__device__ __forceinline__ void gl_lds16(const void* g, void* l) {
  __builtin_amdgcn_global_load_lds((__attribute__((address_space(1))) void*)g,
                                   (__attribute__((address_space(3))) void*)l,
                                   16, 0, 0);
}

// ---- X fp32 -> bf16 ----
__global__ __launch_bounds__(256) void cvt_kernel(const float* __restrict__ Xq,
                                                  const float* __restrict__ Xkv,
                                                  bf16* __restrict__ Xb) {
  const float* src = blockIdx.y ? Xkv : Xq;
  bf16* dst = Xb + (size_t)blockIdx.y * (8192 * 1024);
  size_t i = ((size_t)blockIdx.x * 256 + threadIdx.x) * 8;
  float4 f0 = ((const float4*)(src + i))[0];
  float4 f1 = ((const float4*)(src + i))[1];
  bf16x8 t = {(bf16)f0.x, (bf16)f0.y, (bf16)f0.z, (bf16)f0.w,
              (bf16)f1.x, (bf16)f1.y, (bf16)f1.z, (bf16)f1.w};
  *(bf16x8*)(dst + i) = t;
}

// ---- W transpose + fp32->bf16: Wt[z][n][k] = W_z[k][n] ----
__global__ __launch_bounds__(256) void wt_kernel(const float* __restrict__ Wq,
                                                 const float* __restrict__ Wk,
                                                 const float* __restrict__ Wv,
                                                 bf16* __restrict__ Wt) {
  __shared__ float s[32][33];
  const int z = blockIdx.z;
  const float* W = (z == 0) ? Wq : ((z == 1) ? Wk : Wv);
  bf16* out = Wt + (size_t)z * HIN_ * NOUT_;
  const int n0 = blockIdx.x * 32, k0 = blockIdx.y * 32;
  const int tx = threadIdx.x, ty = threadIdx.y;
#pragma unroll
  for (int i = 0; i < 4; i++)
    s[ty + i * 8][tx] = W[(size_t)(k0 + ty + i * 8) * NOUT_ + n0 + tx];
  __syncthreads();
#pragma unroll
  for (int i = 0; i < 4; i++)
    out[(size_t)(n0 + ty + i * 8) * HIN_ + k0 + tx] = (bf16)s[tx][ty + i * 8];
}

// ---- QKV projection, all-bf16, 128x128 tile, BK=64 ----
// grid (64, 8, 3). z<2: mt=bx (XCD=mt%8 -> A-tiles L2-resident), nt=by.
// z=2: nt=bx (XCD=nt%8 -> Xkv-tiles L2-resident), mt=by.
__global__ __launch_bounds__(256, 4) void proj_kernel(const bf16* __restrict__ Xb,
                                                      const bf16* __restrict__ Wt,
                                                      bf16* __restrict__ Qb,
                                                      bf16* __restrict__ Kb,
                                                      bf16* __restrict__ Vtb) {
  __shared__ bf16 As[128 * 64];
  __shared__ bf16 Bs[128 * 64];
  const int z = blockIdx.z;
  const bf16* Abase = (z == 0) ? Xb : ((z == 1) ? Xb + (size_t)8192 * 1024 : Wt + (size_t)2 * HIN_ * NOUT_);
  const bf16* Bbase = (z == 0) ? Wt : ((z == 1) ? Wt + (size_t)HIN_ * NOUT_ : Xb + (size_t)8192 * 1024);
  const int mt = (z == 2) ? blockIdx.y : blockIdx.x;
  const int nt = (z == 2) ? blockIdx.x : blockIdx.y;
  const int m0 = mt * 128, n0 = nt * 128;
  const int tid = threadIdx.x;
  const int w = tid >> 6, lane = tid & 63, quad = lane >> 4, lo = lane & 15;
  const int wm = (w >> 1) * 64, wn = (w & 1) * 64;
  const int srow = w * 8 + (lane >> 3);
  const int schunk = (lane & 7) ^ (srow & 7);

  f32x4 acc[4][4] = {};

  for (int k0 = 0; k0 < HIN_; k0 += 64) {
    __syncthreads();
#pragma unroll
    for (int j = 0; j < 4; j++) {
      int row = j * 32 + srow;
      gl_lds16(Abase + (size_t)(m0 + row) * HIN_ + k0 + schunk * 8, As + (j * 32 + w * 8) * 64);
      gl_lds16(Bbase + (size_t)(n0 + row) * HIN_ + k0 + schunk * 8, Bs + (j * 32 + w * 8) * 64);
    }
    __syncthreads();
#pragma unroll
    for (int kk = 0; kk < 2; kk++) {
      bf16x8 bfrag[4], afrag[4];
#pragma unroll
      for (int j = 0; j < 4; j++) {
        int off = ((((kk << 2) + quad) ^ (lo & 7)) << 3);
        bfrag[j] = *(const bf16x8*)(Bs + (wn + j * 16 + lo) * 64 + off);
        afrag[j] = *(const bf16x8*)(As + (wm + j * 16 + lo) * 64 + off);
      }
#pragma unroll
      for (int i = 0; i < 4; i++)
#pragma unroll
        for (int j = 0; j < 4; j++)
          acc[i][j] = __builtin_amdgcn_mfma_f32_16x16x32_bf16(afrag[i], bfrag[j], acc[i][j], 0, 0, 0);
    }
  }

#pragma unroll
  for (int i = 0; i < 4; i++)
#pragma unroll
    for (int j = 0; j < 4; j++)
#pragma unroll
      for (int r = 0; r < 4; r++) {
        int m = m0 + wm + i * 16 + quad * 4 + r;
        int n = n0 + wn + j * 16 + lo;
        float v = acc[i][j][r];
        if (z == 2) {
          int h = m >> 6, e = m & 63, b = n >> 11, t = n & 2047;
          Vtb[(((size_t)b * H_ + h) * E_ + e) * T_ + t] = (bf16)v;
        } else {
          int b = m >> 11, t = m & 2047, h = n >> 6, e = n & 63;
          if (z == 0)
            Qb[(((size_t)b * H_ + h) * T_ + t) * E_ + e] = (bf16)(v * QSCALE);
          else
            Kb[(((size_t)b * H_ + h) * T_ + t) * E_ + e] = (bf16)(v * QKSCALE);
        }
      }
}

// ---- Flash attention: 2-wave blocks, 128 q/block (64 q/wave), 64-key tiles ----
__global__ __launch_bounds__(128, 2) void attn_kernel(const bf16* __restrict__ Qb,
                                                      const bf16* __restrict__ Kb,
                                                      const bf16* __restrict__ Vtb,
                                                      float* __restrict__ out) {
  __shared__ bf16 Ks[64 * 64];
  __shared__ bf16 Vts[64 * 64];
  const int tid = threadIdx.x;
  const int w = tid >> 6, lane = tid & 63, quad = lane >> 4, lo = lane & 15;
  const int bh = blockIdx.x, q0 = blockIdx.y * 128;
  const int wq = q0 + w * 64;
  const bf16* Qg = Qb + (size_t)bh * T_ * E_;
  const bf16* Kg = Kb + (size_t)bh * T_ * E_;
  const bf16* Vg = Vtb + (size_t)bh * E_ * T_;
  const int srow = lane >> 3;                 // 0..7 within 8-row staging group
  const int schunk = (lane & 7) ^ (srow & 7); // XOR'd source chunk

  // Q fragments in registers (B-operand: n=lo -> q, k=quad*8+j -> e)
  bf16x8 qf[4][2];
#pragma unroll
  for (int qi = 0; qi < 4; qi++)
#pragma unroll
    for (int ks = 0; ks < 2; ks++)
      qf[qi][ks] = *(const bf16x8*)(Qg + (size_t)(wq + qi * 16 + lo) * E_ + ks * 32 + quad * 8);

  f32x4 acc[4][4] = {};
  float lsum[4] = {0.f, 0.f, 0.f, 0.f};

  for (int kt = 0; kt < T_ / 64; kt++) {
    __syncthreads();
    // wave w stages K rows [32w,32w+32) and V rows [32w,32w+32), 4 insts each
#pragma unroll
    for (int i = 0; i < 4; i++) {
      int row = w * 32 + i * 8 + srow;
      gl_lds16(Kg + (size_t)(kt * 64 + row) * E_ + schunk * 8, Ks + (w * 32 + i * 8) * 64);
      gl_lds16(Vg + (size_t)row * T_ + kt * 64 + schunk * 8, Vts + (w * 32 + i * 8) * 64);
    }
    __syncthreads();

    // K fragments (A-operand: m=lo -> t, k=quad*8+j -> e)
    bf16x8 kf[4][2];
#pragma unroll
    for (int ti = 0; ti < 4; ti++)
#pragma unroll
      for (int ks = 0; ks < 2; ks++)
        kf[ti][ks] = *(const bf16x8*)(Ks + (ti * 16 + lo) * 64 + ((((ks << 2) + quad) ^ (lo & 7)) << 3));

    // S^T tiles + exp2 -> P fragments (A-layout for 16x16x16)
    bf16x4 pf[4][4];
#pragma unroll
    for (int qi = 0; qi < 4; qi++) {
      f32x4 st[4] = {};
#pragma unroll
      for (int ks = 0; ks < 2; ks++)
#pragma unroll
        for (int ti = 0; ti < 4; ti++)
          st[ti] = __builtin_amdgcn_mfma_f32_16x16x32_bf16(kf[ti][ks], qf[qi][ks], st[ti], 0, 0, 0);
      float ls = 0.f;
#pragma unroll
      for (int ti = 0; ti < 4; ti++) {
        bf16x4 p4;
#pragma unroll
        for (int r = 0; r < 4; r++) {
          float p = __builtin_amdgcn_exp2f(st[ti][r]);  // raw v_exp_f32
          ls += p;
          p4[r] = (bf16)p;
        }
        pf[qi][ti] = p4;
      }
      lsum[qi] += ls;
    }

    // O += P @ V via 16x16x16 (B-operand: n=lo -> e, k=quad*4+j -> t)
#pragma unroll
    for (int tc = 0; tc < 4; tc++)
#pragma unroll
      for (int ej = 0; ej < 4; ej++) {
        bf16x4 vf = *(const bf16x4*)(Vts + (ej * 16 + lo) * 64 +
                                     (((tc * 2 + (quad >> 1)) ^ (lo & 7)) << 3) + (quad & 1) * 4);
#pragma unroll
        for (int qi = 0; qi < 4; qi++)
          acc[qi][ej] = __builtin_amdgcn_mfma_f32_16x16x16bf16_1k(
              __builtin_bit_cast(s16x4, pf[qi][tc]), __builtin_bit_cast(s16x4, vf),
              acc[qi][ej], 0, 0, 0);
      }
  }

  const int b = bh >> 4, h = bh & 15;
#pragma unroll
  for (int qi = 0; qi < 4; qi++) {
    float l = lsum[qi];
    l += __shfl_xor(l, 16);
    l += __shfl_xor(l, 32);  // all quads hold full sum for q = qi*16+lo
#pragma unroll
    for (int r = 0; r < 4; r++) {
      float linv = __builtin_amdgcn_rcpf(__shfl(l, quad * 4 + r));
      size_t t = q0 + w * 64 + qi * 16 + quad * 4 + r;
#pragma unroll
      for (int ej = 0; ej < 4; ej++)
        out[((size_t)b * T_ + t) * NOUT_ + h * E_ + ej * 16 + lo] = acc[qi][ej][r] * linv;
    }
  }
}

extern "C" void kernel_launch(void* const* d_in, const int* in_sizes, int n_in,
                              void* d_out, int out_size, void* d_ws, size_t ws_size,
                              hipStream_t stream) {
  const float* Xq  = (const float*)d_in[0];
  const float* Xkv = (const float*)d_in[1];
  const float* Wq  = (const float*)d_in[2];
  const float* Wk  = (const float*)d_in[3];
  const float* Wv  = (const float*)d_in[4];
  float* out = (float*)d_out;

  char* ws = (char*)d_ws;
  bf16* Qb  = (bf16*)(ws);                        // 16 MB [B][H][T][E]
  bf16* Kb  = (bf16*)(ws + ((size_t)16 << 20));   // 16 MB [B][H][T][E]
  bf16* Vtb = (bf16*)(ws + ((size_t)32 << 20));   // 16 MB [B][H][E][T]
  bf16* Wt  = (bf16*)(ws + ((size_t)48 << 20));   // 6 MB  3 x [N][K]
  bf16* Xb  = (bf16*)d_out;                       // 32 MB scratch (d_out unread until attn)

  hipLaunchKernelGGL(cvt_kernel, dim3(4096, 2), dim3(256), 0, stream, Xq, Xkv, Xb);
  hipLaunchKernelGGL(wt_kernel, dim3(32, 32, 3), dim3(32, 8), 0, stream, Wq, Wk, Wv, Wt);
  hipLaunchKernelGGL(proj_kernel, dim3(64, 8, 3), dim3(256), 0, stream, Xb, Wt, Qb, Kb, Vtb);
  hipLaunchKernelGGL(attn_kernel, dim3(64, 16), dim3(128), 0, stream, Qb, Kb, Vtb, out);
}